// Round 11
// baseline (183.039 us; speedup 1.0000x reference)
//
#include <hip/hip_runtime.h>
#include <hip/hip_bf16.h>

// GCNConv: out = segment_sum(edge_vals * (x@W)[edge_col], edge_row)
// Phase 1: Wt = bf16(W^T); h = x@W via bf16 MFMA, x staged through LDS with
//          global_load_lds (64-row tile, 64KB, pre-swizzled global source so
//          ds_read_b128 is bank-conflict-free; rule #21 both-sides swizzle).
// Phase 2: ATOMIC-FREE bucket counting sort (bucket = 64 rows):
//   hist -> colscan -> basescan -> scatter (LDS atomics only) -> bucket_rowsum.

#define IN_F  256
#define OUT_F 128
#define BSH   6        // 64 rows per bucket
#define CH    4096     // edges per chunk block
#define CAP   1536     // LDS sorted-bucket capacity (avg 1024, +16 sigma)

typedef __attribute__((ext_vector_type(8))) short sh8;
typedef __attribute__((ext_vector_type(4))) float f32x4;

__device__ __forceinline__ unsigned short f2bf(float f) {
    unsigned u = __float_as_uint(f);
    unsigned r = u + 0x7fff + ((u >> 16) & 1);   // round-to-nearest-even
    return (unsigned short)(r >> 16);
}
__device__ __forceinline__ float bf2f(unsigned short s) {
    return __uint_as_float(((unsigned)s) << 16);
}

// ---------------- Wt[n][k] = bf16(W[k][n]) ----------------
__global__ __launch_bounds__(256) void wt_prep_kernel(
    const float* __restrict__ w, unsigned short* __restrict__ wt) {
    int i = blockIdx.x * 256 + threadIdx.x;     // 32768 elements
    int k = i >> 7, n = i & 127;
    wt[n * IN_F + k] = f2bf(w[i]);
}

// ---------------- h = x@W via MFMA, LDS-staged x ----------------
// Block: 256 thr = 4 waves; 64 rows. Wave w stages rows {r*4+w}, computes
// rows w*16..w*16+15. LDS layout: row-major 1KB rows, 16B granules swizzled
// by granule^(row&15) -- applied on the GLOBAL source (linear LDS dest, m104)
// and on the ds_read address (both sides, rule #21).
__global__ __launch_bounds__(256) void gemm_mfma_kernel(
    const float* __restrict__ x, const unsigned short* __restrict__ wt,
    unsigned short* __restrict__ h, int n_nodes) {
    __shared__ float xs[64 * 256];   // 64 KB
    int tid = threadIdx.x;
    int w = tid >> 6, lane = tid & 63;
    long blk0 = (long)blockIdx.x * 64;
    long rmax = n_nodes - 1;

    // ---- stage: 16 fire-and-forget global_load_lds x 16B per thread ----
    #pragma unroll
    for (int r = 0; r < 16; r++) {
        int row = r * 4 + w;                      // wave-uniform
        int lg = lane ^ (row & 15);               // pre-swizzled source granule
        long grow = blk0 + row; if (grow > rmax) grow = rmax;
        const float* src = x + grow * IN_F + lg * 4;
        __builtin_amdgcn_global_load_lds(
            (const __attribute__((address_space(1))) void*)src,
            (__attribute__((address_space(3))) void*)((char*)xs + row * 1024),
            16, 0, 0);
    }
    __syncthreads();

    int l16 = lane & 15, hi = lane >> 4;
    int row_l = w * 16 + l16;                     // LDS row this lane reads
    const char* xrow = (const char*)xs + row_l * 1024;
    const unsigned short* wp = wt + l16 * IN_F + hi * 8;

    f32x4 acc[8];
    #pragma unroll
    for (int nt = 0; nt < 8; nt++)
        acc[nt] = (f32x4){0.f, 0.f, 0.f, 0.f};

    #pragma unroll
    for (int ks = 0; ks < 8; ks++) {
        int g0 = hi * 2 + ks * 8;
        int p0 = g0 ^ l16;                        // swizzled read granule
        int p1 = (g0 + 1) ^ l16;
        float4 t0 = *(const float4*)(xrow + p0 * 16);
        float4 t1 = *(const float4*)(xrow + p1 * 16);
        sh8 a;
        a[0] = (short)f2bf(t0.x); a[1] = (short)f2bf(t0.y);
        a[2] = (short)f2bf(t0.z); a[3] = (short)f2bf(t0.w);
        a[4] = (short)f2bf(t1.x); a[5] = (short)f2bf(t1.y);
        a[6] = (short)f2bf(t1.z); a[7] = (short)f2bf(t1.w);
        int k0 = ks * 32;
        #pragma unroll
        for (int nt = 0; nt < 8; nt++) {
            sh8 b = *(const sh8*)(wp + nt * 16 * IN_F + k0);
            acc[nt] = __builtin_amdgcn_mfma_f32_16x16x32_bf16(
                a, b, acc[nt], 0, 0, 0);
        }
    }

    int rbase = hi * 4;
    #pragma unroll
    for (int j = 0; j < 4; j++) {
        long r = blk0 + w * 16 + rbase + j;
        if (r < n_nodes) {
            unsigned short* hp = h + r * OUT_F + l16;
            #pragma unroll
            for (int nt = 0; nt < 8; nt++)
                hp[nt * 16] = f2bf(acc[nt][j]);
        }
    }
}

// ---------------- hist: T[b][k] = #edges of block b in bucket k -----------
__global__ __launch_bounds__(256) void hist_kernel(
    const int* __restrict__ erow, int* __restrict__ T,
    int n_edges, int nbuck) {
    __shared__ int lh[2048];
    int tid = threadIdx.x, b = blockIdx.x;
    for (int k = tid; k < nbuck; k += 256) lh[k] = 0;
    __syncthreads();
    int s = b * CH, e = min(s + CH, n_edges);
    for (int i = s + tid; i < e; i += 256)
        atomicAdd(&lh[erow[i] >> BSH], 1);
    __syncthreads();
    int* Tr = T + (long)b * nbuck;
    for (int k = tid; k < nbuck; k += 256) Tr[k] = lh[k];
}

// ---------------- colscan: T[b][k] -> prefix over b; colTotal[k] ----------
__global__ __launch_bounds__(256) void colscan_kernel(
    int* __restrict__ T, int* __restrict__ colTotal, int nblk, int nbuck) {
    int k = blockIdx.x * 4 + (threadIdx.x >> 6);
    int lane = threadIdx.x & 63;
    if (k >= nbuck) return;
    int carry = 0;
    for (int c = 0; c < nblk; c += 64) {
        int b = c + lane;
        int v = (b < nblk) ? T[(long)b * nbuck + k] : 0;
        int incl = v;
        #pragma unroll
        for (int off = 1; off < 64; off <<= 1) {
            int t = __shfl_up(incl, off);
            if (lane >= off) incl += t;
        }
        if (b < nblk) T[(long)b * nbuck + k] = carry + incl - v;
        carry += __shfl(incl, 63);
    }
    if (lane == 0) colTotal[k] = carry;
}

// ---------------- basescan: bucketBase = exclusive scan(colTotal) ---------
__global__ __launch_bounds__(256) void basescan_kernel(
    const int* __restrict__ colTotal, int* __restrict__ base, int nbuck) {
    __shared__ int s[256];
    int tid = threadIdx.x;
    int loc[8];
    int sum = 0;
    #pragma unroll
    for (int j = 0; j < 8; j++) {
        int i = tid * 8 + j;
        loc[j] = (i < nbuck) ? colTotal[i] : 0;
        sum += loc[j];
    }
    s[tid] = sum;
    __syncthreads();
    for (int off = 1; off < 256; off <<= 1) {
        int t = (tid >= off) ? s[tid - off] : 0;
        __syncthreads();
        s[tid] += t;
        __syncthreads();
    }
    int pre = s[tid] - sum;
    #pragma unroll
    for (int j = 0; j < 8; j++) {
        int i = tid * 8 + j;
        if (i < nbuck) base[i] = pre;
        pre += loc[j];
    }
    if (tid == 255) base[nbuck] = pre;    // == n_edges
}

// ---------------- scatter: exact positions via LDS atomics ----------------
__global__ __launch_bounds__(256) void scatter_kernel(
    const int* __restrict__ erow, const int* __restrict__ ecol,
    const float* __restrict__ eval, const int* __restrict__ T,
    const int* __restrict__ base, unsigned long long* __restrict__ epack,
    int n_edges, int nbuck) {
    __shared__ int lpos[2048];
    int tid = threadIdx.x, b = blockIdx.x;
    const int* Tr = T + (long)b * nbuck;
    for (int k = tid; k < nbuck; k += 256) lpos[k] = base[k] + Tr[k];
    __syncthreads();
    int s = b * CH, e = min(s + CH, n_edges);
    for (int i = s + tid; i < e; i += 256) {
        int r = erow[i];
        int c = ecol[i];
        float v = eval[i];
        int p = atomicAdd(&lpos[r >> BSH], 1);
        epack[p] = ((unsigned long long)__float_as_uint(v) << 32)
                 | ((unsigned)(r & 63) << 17) | (unsigned)c;
    }
}

// ---------------- bucket_rowsum: block/bucket, LDS sort, gather -----------
__global__ __launch_bounds__(256) void bucket_rowsum_kernel(
    const unsigned short* __restrict__ h, const int* __restrict__ base,
    const unsigned long long* __restrict__ epack,
    float* __restrict__ out, int n_nodes, int nbuck) {
    __shared__ unsigned long long sorted[CAP];
    __shared__ int lh[64], lo[64], lc[64];
    int tid = threadIdx.x, k = blockIdx.x;
    int s = base[k], e = base[k + 1];
    int size = e - s;
    int wv = tid >> 6, lane = tid & 63;

    if (tid < 64) { lh[tid] = 0; lc[tid] = 0; }
    __syncthreads();
    for (int i = tid; i < size; i += 256) {
        unsigned lo32 = (unsigned)(epack[s + i] & 0xffffffffu);
        atomicAdd(&lh[(lo32 >> 17) & 63], 1);
    }
    __syncthreads();
    if (tid < 64) {
        int v = lh[tid];
        int incl = v;
        #pragma unroll
        for (int off = 1; off < 64; off <<= 1) {
            int t = __shfl_up(incl, off);
            if (lane >= off) incl += t;
        }
        lo[tid] = incl - v;
    }
    __syncthreads();
    bool fits = (size <= CAP);
    if (fits) {
        for (int i = tid; i < size; i += 256) {
            unsigned long long ed = epack[s + i];
            int r = (int)((ed >> 17) & 63);
            int p = atomicAdd(&lc[r], 1) + lo[r];
            sorted[p] = ed;
        }
    }
    __syncthreads();

    for (int rr = 0; rr < 16; rr++) {
        int r = wv * 16 + rr;
        long row = (long)k * 64 + r;
        if (row >= n_nodes) break;
        int rs = lo[r], cnt = lh[r];
        float a0 = 0.f, a1 = 0.f;
        if (fits) {
            int j = 0;
            for (; j + 4 <= cnt; j += 4) {
                unsigned long long e0 = sorted[rs + j];
                unsigned long long e1 = sorted[rs + j + 1];
                unsigned long long e2 = sorted[rs + j + 2];
                unsigned long long e3 = sorted[rs + j + 3];
                unsigned hv0 = *((const unsigned*)(h + (long)(e0 & 0x1ffffu) * OUT_F) + lane);
                unsigned hv1 = *((const unsigned*)(h + (long)(e1 & 0x1ffffu) * OUT_F) + lane);
                unsigned hv2 = *((const unsigned*)(h + (long)(e2 & 0x1ffffu) * OUT_F) + lane);
                unsigned hv3 = *((const unsigned*)(h + (long)(e3 & 0x1ffffu) * OUT_F) + lane);
                float v0 = __uint_as_float((unsigned)(e0 >> 32));
                float v1 = __uint_as_float((unsigned)(e1 >> 32));
                float v2 = __uint_as_float((unsigned)(e2 >> 32));
                float v3 = __uint_as_float((unsigned)(e3 >> 32));
                a0 += v0 * bf2f((unsigned short)(hv0 & 0xffff));
                a1 += v0 * bf2f((unsigned short)(hv0 >> 16));
                a0 += v1 * bf2f((unsigned short)(hv1 & 0xffff));
                a1 += v1 * bf2f((unsigned short)(hv1 >> 16));
                a0 += v2 * bf2f((unsigned short)(hv2 & 0xffff));
                a1 += v2 * bf2f((unsigned short)(hv2 >> 16));
                a0 += v3 * bf2f((unsigned short)(hv3 & 0xffff));
                a1 += v3 * bf2f((unsigned short)(hv3 >> 16));
            }
            for (; j < cnt; j++) {
                unsigned long long e0 = sorted[rs + j];
                unsigned hv0 = *((const unsigned*)(h + (long)(e0 & 0x1ffffu) * OUT_F) + lane);
                float v0 = __uint_as_float((unsigned)(e0 >> 32));
                a0 += v0 * bf2f((unsigned short)(hv0 & 0xffff));
                a1 += v0 * bf2f((unsigned short)(hv0 >> 16));
            }
        } else {
            for (int i = 0; i < size; i++) {
                unsigned long long ed = epack[s + i];
                if ((int)((ed >> 17) & 63) == r) {
                    unsigned hv0 = *((const unsigned*)(h + (long)(ed & 0x1ffffu) * OUT_F) + lane);
                    float v0 = __uint_as_float((unsigned)(ed >> 32));
                    a0 += v0 * bf2f((unsigned short)(hv0 & 0xffff));
                    a1 += v0 * bf2f((unsigned short)(hv0 >> 16));
                }
            }
        }
        float2 o; o.x = a0; o.y = a1;
        *(float2*)(out + row * OUT_F + lane * 2) = o;
    }
}

extern "C" void kernel_launch(void* const* d_in, const int* in_sizes, int n_in,
                              void* d_out, int out_size, void* d_ws, size_t ws_size,
                              hipStream_t stream) {
    const float* x    = (const float*)d_in[0];
    const float* w    = (const float*)d_in[1];
    const int*   erow = (const int*)d_in[2];
    const int*   ecol = (const int*)d_in[3];
    const float* eval = (const float*)d_in[4];
    float* out = (float*)d_out;

    int n_nodes = in_sizes[0] / IN_F;
    int n_edges = in_sizes[2];
    int nbuck = (n_nodes + 63) >> BSH;            // 1563
    int nblk  = (n_edges + CH - 1) / CH;          // 391

    // workspace layout (256B aligned)
    char* p = (char*)d_ws;
    auto alloc = [&](size_t bytes) {
        char* q = p;
        p += (bytes + 255) & ~(size_t)255;
        return q;
    };
    unsigned short* h  = (unsigned short*)alloc((size_t)n_nodes * OUT_F * 2);
    int* T        = (int*)alloc((size_t)nblk * nbuck * 4);
    int* colTotal = (int*)alloc((size_t)nbuck * 4);
    int* base     = (int*)alloc((size_t)(nbuck + 1) * 4);
    unsigned long long* epack = (unsigned long long*)alloc((size_t)n_edges * 8);
    unsigned short* wt = (unsigned short*)alloc((size_t)IN_F * OUT_F * 2);

    wt_prep_kernel<<<dim3((IN_F * OUT_F) / 256), 256, 0, stream>>>(w, wt);
    gemm_mfma_kernel<<<dim3((n_nodes + 63) / 64), 256, 0, stream>>>(
        x, wt, h, n_nodes);

    hist_kernel<<<dim3(nblk), 256, 0, stream>>>(erow, T, n_edges, nbuck);
    colscan_kernel<<<dim3((nbuck + 3) / 4), 256, 0, stream>>>(
        T, colTotal, nblk, nbuck);
    basescan_kernel<<<dim3(1), 256, 0, stream>>>(colTotal, base, nbuck);
    scatter_kernel<<<dim3(nblk), 256, 0, stream>>>(
        erow, ecol, eval, T, base, epack, n_edges, nbuck);

    bucket_rowsum_kernel<<<dim3(nbuck), 256, 0, stream>>>(
        h, base, epack, out, n_nodes, nbuck);
}

// Round 12
// 165.287 us; speedup vs baseline: 1.1074x; 1.1074x over previous
//
#include <hip/hip_runtime.h>
#include <hip/hip_bf16.h>

// GCNConv: out = segment_sum(edge_vals * (x@W)[edge_col], edge_row)
// Phase 1: Wt = bf16(W^T); h = x@W via bf16 MFMA, register double-buffered
//          K-loop (explicit 2-stage pipeline; launch_bounds(256,1) frees VGPRs).
// Phase 2: ATOMIC-FREE bucket counting sort (bucket = 64 rows):
//   hist -> colscan -> basescan -> scatter (LDS atomics only) -> bucket_rowsum.

#define IN_F  256
#define OUT_F 128
#define BSH   6        // 64 rows per bucket
#define CH    4096     // edges per chunk block
#define CAP   1536     // LDS sorted-bucket capacity (avg 1024, +16 sigma)

typedef __attribute__((ext_vector_type(8))) short sh8;
typedef __attribute__((ext_vector_type(4))) float f32x4;

__device__ __forceinline__ unsigned short f2bf(float f) {
    unsigned u = __float_as_uint(f);
    unsigned r = u + 0x7fff + ((u >> 16) & 1);   // round-to-nearest-even
    return (unsigned short)(r >> 16);
}
__device__ __forceinline__ float bf2f(unsigned short s) {
    return __uint_as_float(((unsigned)s) << 16);
}

// ---------------- Wt[n][k] = bf16(W[k][n]) ----------------
__global__ __launch_bounds__(256) void wt_prep_kernel(
    const float* __restrict__ w, unsigned short* __restrict__ wt) {
    int i = blockIdx.x * 256 + threadIdx.x;     // 32768 elements
    int k = i >> 7, n = i & 127;
    wt[n * IN_F + k] = f2bf(w[i]);
}

// ---------------- h = x@W via MFMA, register-pipelined ----------------
__global__ __launch_bounds__(256, 1) void gemm_mfma_kernel(
    const float* __restrict__ x, const unsigned short* __restrict__ wt,
    unsigned short* __restrict__ h, int n_nodes) {
    int tid = threadIdx.x;
    int wv = tid >> 6, l = tid & 63;
    int l16 = l & 15, lk = (l >> 4) * 8;
    long row0 = (long)blockIdx.x * 128 + wv * 32;

    long rmax = n_nodes - 1;
    long ra0 = row0 + l16;      if (ra0 > rmax) ra0 = rmax;
    long ra1 = row0 + 16 + l16; if (ra1 > rmax) ra1 = rmax;
    const float* xp0 = x + ra0 * IN_F + lk;
    const float* xp1 = x + ra1 * IN_F + lk;
    const unsigned short* wp = wt + l16 * IN_F + lk;

    f32x4 acc[2][8];
    #pragma unroll
    for (int rt = 0; rt < 2; rt++)
        #pragma unroll
        for (int nt = 0; nt < 8; nt++)
            acc[rt][nt] = (f32x4){0.f, 0.f, 0.f, 0.f};

    float4 tA0, tA1, tA2, tA3, tB0, tB1, tB2, tB3;

    // preload ks=0
    tA0 = *(const float4*)(xp0);
    tA1 = *(const float4*)(xp0 + 4);
    tA2 = *(const float4*)(xp1);
    tA3 = *(const float4*)(xp1 + 4);

#define COMPUTE_STEP(T0, T1, T2, T3, K0)                                   \
    {                                                                       \
        sh8 a0, a1;                                                         \
        a0[0] = (short)f2bf(T0.x); a0[1] = (short)f2bf(T0.y);               \
        a0[2] = (short)f2bf(T0.z); a0[3] = (short)f2bf(T0.w);               \
        a0[4] = (short)f2bf(T1.x); a0[5] = (short)f2bf(T1.y);               \
        a0[6] = (short)f2bf(T1.z); a0[7] = (short)f2bf(T1.w);               \
        a1[0] = (short)f2bf(T2.x); a1[1] = (short)f2bf(T2.y);               \
        a1[2] = (short)f2bf(T2.z); a1[3] = (short)f2bf(T2.w);               \
        a1[4] = (short)f2bf(T3.x); a1[5] = (short)f2bf(T3.y);               \
        a1[6] = (short)f2bf(T3.z); a1[7] = (short)f2bf(T3.w);               \
        _Pragma("unroll")                                                   \
        for (int nt = 0; nt < 8; nt++) {                                    \
            sh8 b = *(const sh8*)(wp + nt * 16 * IN_F + (K0));              \
            acc[0][nt] = __builtin_amdgcn_mfma_f32_16x16x32_bf16(           \
                a0, b, acc[0][nt], 0, 0, 0);                                \
            acc[1][nt] = __builtin_amdgcn_mfma_f32_16x16x32_bf16(           \
                a1, b, acc[1][nt], 0, 0, 0);                                \
        }                                                                   \
    }

    #pragma unroll
    for (int ks = 0; ks < 8; ks += 2) {
        int k1 = (ks + 1) * 32;
        tB0 = *(const float4*)(xp0 + k1);
        tB1 = *(const float4*)(xp0 + k1 + 4);
        tB2 = *(const float4*)(xp1 + k1);
        tB3 = *(const float4*)(xp1 + k1 + 4);
        COMPUTE_STEP(tA0, tA1, tA2, tA3, ks * 32);
        if (ks + 2 < 8) {
            int k2 = (ks + 2) * 32;
            tA0 = *(const float4*)(xp0 + k2);
            tA1 = *(const float4*)(xp0 + k2 + 4);
            tA2 = *(const float4*)(xp1 + k2);
            tA3 = *(const float4*)(xp1 + k2 + 4);
        }
        COMPUTE_STEP(tB0, tB1, tB2, tB3, k1);
    }
#undef COMPUTE_STEP

    int rbase = (l >> 4) * 4;
    #pragma unroll
    for (int rt = 0; rt < 2; rt++) {
        #pragma unroll
        for (int j = 0; j < 4; j++) {
            long r = row0 + rt * 16 + rbase + j;
            if (r < n_nodes) {
                unsigned short* hp = h + r * OUT_F + l16;
                #pragma unroll
                for (int nt = 0; nt < 8; nt++)
                    hp[nt * 16] = f2bf(acc[rt][nt][j]);
            }
        }
    }
}

// ---------------- hist: T[b][k] = #edges of block b in bucket k -----------
__global__ __launch_bounds__(256) void hist_kernel(
    const int* __restrict__ erow, int* __restrict__ T,
    int n_edges, int nbuck) {
    __shared__ int lh[2048];
    int tid = threadIdx.x, b = blockIdx.x;
    for (int k = tid; k < nbuck; k += 256) lh[k] = 0;
    __syncthreads();
    int s = b * CH, e = min(s + CH, n_edges);
    for (int i = s + tid; i < e; i += 256)
        atomicAdd(&lh[erow[i] >> BSH], 1);
    __syncthreads();
    int* Tr = T + (long)b * nbuck;
    for (int k = tid; k < nbuck; k += 256) Tr[k] = lh[k];
}

// ---------------- colscan: T[b][k] -> prefix over b; colTotal[k] ----------
__global__ __launch_bounds__(256) void colscan_kernel(
    int* __restrict__ T, int* __restrict__ colTotal, int nblk, int nbuck) {
    int k = blockIdx.x * 4 + (threadIdx.x >> 6);
    int lane = threadIdx.x & 63;
    if (k >= nbuck) return;
    int carry = 0;
    for (int c = 0; c < nblk; c += 64) {
        int b = c + lane;
        int v = (b < nblk) ? T[(long)b * nbuck + k] : 0;
        int incl = v;
        #pragma unroll
        for (int off = 1; off < 64; off <<= 1) {
            int t = __shfl_up(incl, off);
            if (lane >= off) incl += t;
        }
        if (b < nblk) T[(long)b * nbuck + k] = carry + incl - v;
        carry += __shfl(incl, 63);
    }
    if (lane == 0) colTotal[k] = carry;
}

// ---------------- basescan: bucketBase = exclusive scan(colTotal) ---------
__global__ __launch_bounds__(256) void basescan_kernel(
    const int* __restrict__ colTotal, int* __restrict__ base, int nbuck) {
    __shared__ int s[256];
    int tid = threadIdx.x;
    int loc[8];
    int sum = 0;
    #pragma unroll
    for (int j = 0; j < 8; j++) {
        int i = tid * 8 + j;
        loc[j] = (i < nbuck) ? colTotal[i] : 0;
        sum += loc[j];
    }
    s[tid] = sum;
    __syncthreads();
    for (int off = 1; off < 256; off <<= 1) {
        int t = (tid >= off) ? s[tid - off] : 0;
        __syncthreads();
        s[tid] += t;
        __syncthreads();
    }
    int pre = s[tid] - sum;
    #pragma unroll
    for (int j = 0; j < 8; j++) {
        int i = tid * 8 + j;
        if (i < nbuck) base[i] = pre;
        pre += loc[j];
    }
    if (tid == 255) base[nbuck] = pre;    // == n_edges
}

// ---------------- scatter: exact positions via LDS atomics ----------------
__global__ __launch_bounds__(256) void scatter_kernel(
    const int* __restrict__ erow, const int* __restrict__ ecol,
    const float* __restrict__ eval, const int* __restrict__ T,
    const int* __restrict__ base, unsigned long long* __restrict__ epack,
    int n_edges, int nbuck) {
    __shared__ int lpos[2048];
    int tid = threadIdx.x, b = blockIdx.x;
    const int* Tr = T + (long)b * nbuck;
    for (int k = tid; k < nbuck; k += 256) lpos[k] = base[k] + Tr[k];
    __syncthreads();
    int s = b * CH, e = min(s + CH, n_edges);
    for (int i = s + tid; i < e; i += 256) {
        int r = erow[i];
        int c = ecol[i];
        float v = eval[i];
        int p = atomicAdd(&lpos[r >> BSH], 1);
        epack[p] = ((unsigned long long)__float_as_uint(v) << 32)
                 | ((unsigned)(r & 63) << 17) | (unsigned)c;
    }
}

// ---------------- bucket_rowsum: block/bucket, LDS sort, gather -----------
__global__ __launch_bounds__(256) void bucket_rowsum_kernel(
    const unsigned short* __restrict__ h, const int* __restrict__ base,
    const unsigned long long* __restrict__ epack,
    float* __restrict__ out, int n_nodes, int nbuck) {
    __shared__ unsigned long long sorted[CAP];
    __shared__ int lh[64], lo[64], lc[64];
    int tid = threadIdx.x, k = blockIdx.x;
    int s = base[k], e = base[k + 1];
    int size = e - s;
    int wv = tid >> 6, lane = tid & 63;

    if (tid < 64) { lh[tid] = 0; lc[tid] = 0; }
    __syncthreads();
    for (int i = tid; i < size; i += 256) {
        unsigned lo32 = (unsigned)(epack[s + i] & 0xffffffffu);
        atomicAdd(&lh[(lo32 >> 17) & 63], 1);
    }
    __syncthreads();
    if (tid < 64) {
        int v = lh[tid];
        int incl = v;
        #pragma unroll
        for (int off = 1; off < 64; off <<= 1) {
            int t = __shfl_up(incl, off);
            if (lane >= off) incl += t;
        }
        lo[tid] = incl - v;
    }
    __syncthreads();
    bool fits = (size <= CAP);
    if (fits) {
        for (int i = tid; i < size; i += 256) {
            unsigned long long ed = epack[s + i];
            int r = (int)((ed >> 17) & 63);
            int p = atomicAdd(&lc[r], 1) + lo[r];
            sorted[p] = ed;
        }
    }
    __syncthreads();

    for (int rr = 0; rr < 16; rr++) {
        int r = wv * 16 + rr;
        long row = (long)k * 64 + r;
        if (row >= n_nodes) break;
        int rs = lo[r], cnt = lh[r];
        float a0 = 0.f, a1 = 0.f;
        if (fits) {
            int j = 0;
            for (; j + 4 <= cnt; j += 4) {
                unsigned long long e0 = sorted[rs + j];
                unsigned long long e1 = sorted[rs + j + 1];
                unsigned long long e2 = sorted[rs + j + 2];
                unsigned long long e3 = sorted[rs + j + 3];
                unsigned hv0 = *((const unsigned*)(h + (long)(e0 & 0x1ffffu) * OUT_F) + lane);
                unsigned hv1 = *((const unsigned*)(h + (long)(e1 & 0x1ffffu) * OUT_F) + lane);
                unsigned hv2 = *((const unsigned*)(h + (long)(e2 & 0x1ffffu) * OUT_F) + lane);
                unsigned hv3 = *((const unsigned*)(h + (long)(e3 & 0x1ffffu) * OUT_F) + lane);
                float v0 = __uint_as_float((unsigned)(e0 >> 32));
                float v1 = __uint_as_float((unsigned)(e1 >> 32));
                float v2 = __uint_as_float((unsigned)(e2 >> 32));
                float v3 = __uint_as_float((unsigned)(e3 >> 32));
                a0 += v0 * bf2f((unsigned short)(hv0 & 0xffff));
                a1 += v0 * bf2f((unsigned short)(hv0 >> 16));
                a0 += v1 * bf2f((unsigned short)(hv1 & 0xffff));
                a1 += v1 * bf2f((unsigned short)(hv1 >> 16));
                a0 += v2 * bf2f((unsigned short)(hv2 & 0xffff));
                a1 += v2 * bf2f((unsigned short)(hv2 >> 16));
                a0 += v3 * bf2f((unsigned short)(hv3 & 0xffff));
                a1 += v3 * bf2f((unsigned short)(hv3 >> 16));
            }
            for (; j < cnt; j++) {
                unsigned long long e0 = sorted[rs + j];
                unsigned hv0 = *((const unsigned*)(h + (long)(e0 & 0x1ffffu) * OUT_F) + lane);
                float v0 = __uint_as_float((unsigned)(e0 >> 32));
                a0 += v0 * bf2f((unsigned short)(hv0 & 0xffff));
                a1 += v0 * bf2f((unsigned short)(hv0 >> 16));
            }
        } else {
            for (int i = 0; i < size; i++) {
                unsigned long long ed = epack[s + i];
                if ((int)((ed >> 17) & 63) == r) {
                    unsigned hv0 = *((const unsigned*)(h + (long)(ed & 0x1ffffu) * OUT_F) + lane);
                    float v0 = __uint_as_float((unsigned)(ed >> 32));
                    a0 += v0 * bf2f((unsigned short)(hv0 & 0xffff));
                    a1 += v0 * bf2f((unsigned short)(hv0 >> 16));
                }
            }
        }
        float2 o; o.x = a0; o.y = a1;
        *(float2*)(out + row * OUT_F + lane * 2) = o;
    }
}

extern "C" void kernel_launch(void* const* d_in, const int* in_sizes, int n_in,
                              void* d_out, int out_size, void* d_ws, size_t ws_size,
                              hipStream_t stream) {
    const float* x    = (const float*)d_in[0];
    const float* w    = (const float*)d_in[1];
    const int*   erow = (const int*)d_in[2];
    const int*   ecol = (const int*)d_in[3];
    const float* eval = (const float*)d_in[4];
    float* out = (float*)d_out;

    int n_nodes = in_sizes[0] / IN_F;
    int n_edges = in_sizes[2];
    int nbuck = (n_nodes + 63) >> BSH;            // 1563
    int nblk  = (n_edges + CH - 1) / CH;          // 391

    // workspace layout (256B aligned)
    char* p = (char*)d_ws;
    auto alloc = [&](size_t bytes) {
        char* q = p;
        p += (bytes + 255) & ~(size_t)255;
        return q;
    };
    unsigned short* h  = (unsigned short*)alloc((size_t)n_nodes * OUT_F * 2);
    int* T        = (int*)alloc((size_t)nblk * nbuck * 4);
    int* colTotal = (int*)alloc((size_t)nbuck * 4);
    int* base     = (int*)alloc((size_t)(nbuck + 1) * 4);
    unsigned long long* epack = (unsigned long long*)alloc((size_t)n_edges * 8);
    unsigned short* wt = (unsigned short*)alloc((size_t)IN_F * OUT_F * 2);

    wt_prep_kernel<<<dim3((IN_F * OUT_F) / 256), 256, 0, stream>>>(w, wt);
    gemm_mfma_kernel<<<dim3((n_nodes + 127) / 128), 256, 0, stream>>>(
        x, wt, h, n_nodes);

    hist_kernel<<<dim3(nblk), 256, 0, stream>>>(erow, T, n_edges, nbuck);
    colscan_kernel<<<dim3((nbuck + 3) / 4), 256, 0, stream>>>(
        T, colTotal, nblk, nbuck);
    basescan_kernel<<<dim3(1), 256, 0, stream>>>(colTotal, base, nbuck);
    scatter_kernel<<<dim3(nblk), 256, 0, stream>>>(
        erow, ecol, eval, T, base, epack, n_edges, nbuck);

    bucket_rowsum_kernel<<<dim3(nbuck), 256, 0, stream>>>(
        h, base, epack, out, n_nodes, nbuck);
}